// Round 15
// baseline (123.513 us; speedup 1.0000x reference)
//
#include <hip/hip_runtime.h>

#define B_  64
#define N_  1024
#define H_  32
#define C_  768
#define D_  8

#define QCHUNKS    4
#define IMG_PER_Q  (B_ / QCHUNKS)          // 16
#define ROWS_PER_Q (IMG_PER_Q * N_)        // 16384
#define NMAIN      512                     // 32 down rows + 32 up rows each
#define NCONVB     32                      // 2 strips each (64 strips/chunk)

__device__ __forceinline__ float qgelu(float v) {
    return v / (1.0f + __expf(-1.702f * v));
}

typedef float f32x4_t __attribute__((ext_vector_type(4)));
__device__ __forceinline__ float4 ntload4(const float4* p) {
    f32x4_t v = __builtin_nontemporal_load((const f32x4_t*)p);
    return make_float4(v.x, v.y, v.z, v.w);
}
__device__ __forceinline__ void ntstore4(float4 v, float4* p) {
    f32x4_t t; t.x = v.x; t.y = v.y; t.z = v.z; t.w = v.w;
    __builtin_nontemporal_store(t, (f32x4_t*)p);
}

__device__ __forceinline__ void reduce8(float* acc, int lane) {
    {
        const bool hi = lane & 1;
#pragma unroll
        for (int j = 0; j < 4; ++j) {
            const float a = acc[j], b = acc[j + 4];
            acc[j] = hi ? b : a;
            acc[j + 4] = hi ? a : b;
        }
#pragma unroll
        for (int j = 0; j < 4; ++j)
            acc[j] += __shfl_xor(acc[j + 4], 1, 64);
    }
    {
        const bool hi = lane & 2;
#pragma unroll
        for (int j = 0; j < 2; ++j) {
            const float a = acc[j], b = acc[j + 2];
            acc[j] = hi ? b : a;
            acc[j + 2] = hi ? a : b;
        }
#pragma unroll
        for (int j = 0; j < 2; ++j)
            acc[j] += __shfl_xor(acc[j + 2], 2, 64);
    }
    {
        const bool hi = lane & 4;
        const float a = acc[0], b = acc[1];
        acc[0] = hi ? b : a;
        acc[1] = hi ? a : b;
        acc[0] += __shfl_xor(acc[1], 4, 64);
    }
    acc[0] += __shfl_xor(acc[0], 8, 64);
    acc[0] += __shfl_xor(acc[0], 16, 64);
    acc[0] += __shfl_xor(acc[0], 32, 64);
}

// ---------------- k_step: copy-pattern fused pipeline step -------------------
// MAIN blocks (512 thr, 48 KB LDS = Wd^T + Wu): each WAVE interleaves, per
// iteration: t2 loads -> 6 nt x loads (down chunk downC) -> up compute + 6 nt
// out stores (chunk upC) -> down compute. Same-wave read/write interleave =
// the m13 copy pattern (3.15r + 3.15w TB/s concurrently).
// CONV blocks: 2 strips each, t1 -> t2 (chunk convC).
__global__ __launch_bounds__(512) void k_step(
    const float* __restrict__ x,  const float* __restrict__ Wd,
    const float* __restrict__ bd, float* __restrict__ t1,
    const float* __restrict__ Wc, const float* __restrict__ bc,
    float* __restrict__ t2,       const float* __restrict__ Wu,
    const float* __restrict__ bu, float* __restrict__ out,
    int downC, int upC, int convC)
{
    __shared__ float smem[2 * D_ * C_];      // 48 KB
    const int tid = threadIdx.x;
    const int bid = blockIdx.x;

    if (bid < NMAIN) {
        // ========================== MAIN role =============================
        float* sWd = smem;                   // transposed: sWd[d*C_+c]
        float* sWu = smem + D_ * C_;         // Wu row-major [d][C]
        for (int i = tid; i < D_ * C_; i += 512) {
            const int c = i >> 3, d = i & 7;
            sWd[d * C_ + c] = Wd[i];
            sWu[i] = Wu[i];
        }
        __syncthreads();

        const int wid  = tid >> 6;           // 0..7
        const int lane = tid & 63;
        const int dl   = 4 * (lane & 1) + 2 * ((lane >> 1) & 1) + ((lane >> 2) & 1);
        const float bias = bd[dl];

        float4 ub[3];
#pragma unroll
        for (int j = 0; j < 3; ++j)
            ub[j] = *(const float4*)&bu[(lane + j * 64) * 4];

        const bool hasD = (downC >= 0);
        const bool hasU = (upC >= 0);
        const int drow0 = downC * ROWS_PER_Q + bid * 32 + wid * 4;
        const int urow0 = upC   * ROWS_PER_Q + bid * 32 + wid * 4;

#pragma unroll 1
        for (int it = 0; it < 2; ++it) {
            // ---- U loads first (L2-hot t2), then D loads (nt, HBM) ----
            float rv0[D_], rv1[D_];
            if (hasU) {
                const float4* rp = (const float4*)(t2 + (size_t)(urow0 + it * 2) * D_);
                const float4 a = rp[0], b = rp[1], c = rp[2], d = rp[3];
                rv0[0]=a.x; rv0[1]=a.y; rv0[2]=a.z; rv0[3]=a.w;
                rv0[4]=b.x; rv0[5]=b.y; rv0[6]=b.z; rv0[7]=b.w;
                rv1[0]=c.x; rv1[1]=c.y; rv1[2]=c.z; rv1[3]=c.w;
                rv1[4]=d.x; rv1[5]=d.y; rv1[6]=d.z; rv1[7]=d.w;
            }
            float4 va[3], vb[3];
            if (hasD) {
                const float4* x0 = (const float4*)(x + (size_t)(drow0 + it * 2) * C_);
                const float4* x1 = x0 + (C_ / 4);
#pragma unroll
                for (int k = 0; k < 3; ++k) {
                    va[k] = ntload4(&x0[k * 64 + lane]);
                    vb[k] = ntload4(&x1[k * 64 + lane]);
                }
            }
            // ---- U compute + nt stores (hides D load latency) ----
            if (hasU) {
                float4 o0[3], o1[3];
#pragma unroll
                for (int j = 0; j < 3; ++j) { o0[j] = ub[j]; o1[j] = ub[j]; }
#pragma unroll
                for (int d = 0; d < D_; ++d) {
#pragma unroll
                    for (int j = 0; j < 3; ++j) {
                        const float4 wv = *(const float4*)&sWu[d * C_ + (lane + j * 64) * 4];
                        o0[j].x += rv0[d] * wv.x; o0[j].y += rv0[d] * wv.y;
                        o0[j].z += rv0[d] * wv.z; o0[j].w += rv0[d] * wv.w;
                        o1[j].x += rv1[d] * wv.x; o1[j].y += rv1[d] * wv.y;
                        o1[j].z += rv1[d] * wv.z; o1[j].w += rv1[d] * wv.w;
                    }
                }
                float* orow = out + (size_t)(urow0 + it * 2) * C_;
#pragma unroll
                for (int j = 0; j < 3; ++j) {
                    ntstore4(o0[j], (float4*)&orow[(lane + j * 64) * 4]);
                    ntstore4(o1[j], (float4*)&orow[C_ + (lane + j * 64) * 4]);
                }
            }
            // ---- D compute ----
            if (hasD) {
                float a0[D_], a1[D_];
#pragma unroll
                for (int d = 0; d < D_; ++d) { a0[d] = 0.0f; a1[d] = 0.0f; }
#pragma unroll
                for (int k = 0; k < 3; ++k) {
#pragma unroll
                    for (int d = 0; d < D_; ++d) {
                        const float4 wv = *(const float4*)&sWd[d * C_ + (k * 64 + lane) * 4];
                        a0[d] += va[k].x * wv.x + va[k].y * wv.y
                               + va[k].z * wv.z + va[k].w * wv.w;
                        a1[d] += vb[k].x * wv.x + vb[k].y * wv.y
                               + vb[k].z * wv.z + vb[k].w * wv.w;
                    }
                }
                reduce8(a0, lane);
                reduce8(a1, lane);
                if (lane < 16) {
                    const float s = (lane & 8) ? a1[0] : a0[0];
                    t1[(size_t)(drow0 + it * 2 + ((lane >> 3) & 1)) * D_ + dl]
                        = qgelu(s + bias);
                }
            }
        }
    } else {
        // ========================== CONV role =============================
        const int half = tid >> 8;           // 0,1
        const int tt   = tid & 255;
        const int idx  = (bid - NMAIN) * 2 + half;    // strip 0..63
        const int img  = convC * IMG_PER_Q + (idx >> 2);
        const int strip = idx & 3;
        const int h0    = strip * 8;
        const float* in = t1 + (size_t)img * N_ * D_;

        float* sIn  = smem + half * 3200;    // 2560 used
        float* sWcb = smem + 6400;           // 576 Wc + 8 bc (shared)

#pragma unroll
        for (int j = 0; j < 10; ++j) {
            const int i   = tt + j * 256;
            const int lr  = i >> 8;
            const int rem = i & 255;
            const int g   = h0 - 1 + lr;
            sIn[i] = (g >= 0 && g < H_) ? in[(size_t)g * H_ * D_ + rem] : 0.0f;
        }
        for (int i = tid; i < 584; i += 512)
            sWcb[i] = (i < 576) ? Wc[i] : bc[i - 576];
        __syncthreads();

        const int lh = tt >> 5;
        const int w  = tt & 31;
        float acc[D_];
#pragma unroll
        for (int co = 0; co < D_; ++co) acc[co] = sWcb[576 + co];
#pragma unroll
        for (int kh = 0; kh < 3; ++kh) {
            const int lrow = lh + kh;
#pragma unroll
            for (int kw = 0; kw < 3; ++kw) {
                const int ww = w + kw - 1;
                if (ww < 0 || ww >= H_) continue;
                const float* ip = &sIn[(lrow * H_ + ww) * D_];
                const float* wp = &sWcb[(kh * 3 + kw) * D_ * D_];
#pragma unroll
                for (int ci = 0; ci < D_; ++ci) {
                    const float iv = ip[ci];
#pragma unroll
                    for (int co = 0; co < D_; ++co)
                        acc[co] += iv * wp[ci * D_ + co];
                }
            }
        }
        float4 o0, o1;
        o0.x = qgelu(acc[0]); o0.y = qgelu(acc[1]);
        o0.z = qgelu(acc[2]); o0.w = qgelu(acc[3]);
        o1.x = qgelu(acc[4]); o1.y = qgelu(acc[5]);
        o1.z = qgelu(acc[6]); o1.w = qgelu(acc[7]);
        float* tp = t2 + ((size_t)img * N_ + (size_t)(h0 + lh) * H_ + w) * D_;
        *(float4*)tp       = o0;
        *(float4*)(tp + 4) = o1;
    }
}

extern "C" void kernel_launch(void* const* d_in, const int* in_sizes, int n_in,
                              void* d_out, int out_size, void* d_ws, size_t ws_size,
                              hipStream_t stream) {
    const float* x  = (const float*)d_in[0];
    const float* Wd = (const float*)d_in[1];
    const float* bd = (const float*)d_in[2];
    const float* Wc = (const float*)d_in[3];
    const float* bc = (const float*)d_in[4];
    const float* Wu = (const float*)d_in[5];
    const float* bu = (const float*)d_in[6];
    float* out = (float*)d_out;

    const int nrows = B_ * N_;                  // 65536
    float* t1 = (float*)d_ws;                   // [nrows][D_] (2 MB)
    float* t2 = t1 + (size_t)nrows * D_;        // [nrows][D_] (2 MB)

    // Pipeline: launch s = down(s) + conv(s-1) + up(s-2), with down/up
    // INTERLEAVED IN THE SAME WAVES of the MAIN blocks.
    for (int s = 0; s < QCHUNKS + 2; ++s) {
        const int downC = (s < QCHUNKS) ? s : -1;
        const int upC   = (s >= 2) ? s - 2 : -1;
        const int convC = (s >= 1 && s <= QCHUNKS) ? s - 1 : -1;
        const int nConv = (convC >= 0) ? NCONVB : 0;
        k_step<<<NMAIN + nConv, 512, 0, stream>>>(
            x, Wd, bd, t1, Wc, bc, t2, Wu, bu, out, downC, upC, convC);
    }
}

// Round 16
// 102.492 us; speedup vs baseline: 1.2051x; 1.2051x over previous
//
#include <hip/hip_runtime.h>

// Problem dims (fixed by setup_inputs): x [B,N,C], adapter dim D, patch grid HxH
#define B_  64
#define N_  1024
#define H_  32
#define C_  768
#define D_  8

__device__ __forceinline__ float qgelu(float v) {
    return v / (1.0f + __expf(-1.702f * v));
}

// non-temporal float4 load/store (emit global_load/store_dwordx4 with nt —
// no L1/L2 allocation for streaming data)
typedef float f32x4_t __attribute__((ext_vector_type(4)));
__device__ __forceinline__ float4 ntload4(const float4* p) {
    f32x4_t v = __builtin_nontemporal_load((const f32x4_t*)p);
    return make_float4(v.x, v.y, v.z, v.w);
}
__device__ __forceinline__ void ntstore4(float4 v, float4* p) {
    f32x4_t t; t.x = v.x; t.y = v.y; t.z = v.z; t.w = v.w;
    __builtin_nontemporal_store(t, (f32x4_t*)p);
}

// 10-shuffle butterfly reduce over d=8: halve d at xor1/2/4, broadcast 8/16/32.
// On return acc[0] holds, in lane l, the full sum for
// dl(l) = 4*(l&1) + 2*((l>>1)&1) + ((l>>2)&1)  (all 8-lane groups identical).
__device__ __forceinline__ void reduce8(float* acc, int lane) {
    {
        const bool hi = lane & 1;
#pragma unroll
        for (int j = 0; j < 4; ++j) {
            const float a = acc[j], b = acc[j + 4];
            acc[j] = hi ? b : a;
            acc[j + 4] = hi ? a : b;
        }
#pragma unroll
        for (int j = 0; j < 4; ++j)
            acc[j] += __shfl_xor(acc[j + 4], 1, 64);
    }
    {
        const bool hi = lane & 2;
#pragma unroll
        for (int j = 0; j < 2; ++j) {
            const float a = acc[j], b = acc[j + 2];
            acc[j] = hi ? b : a;
            acc[j + 2] = hi ? a : b;
        }
#pragma unroll
        for (int j = 0; j < 2; ++j)
            acc[j] += __shfl_xor(acc[j + 2], 2, 64);
    }
    {
        const bool hi = lane & 4;
        const float a = acc[0], b = acc[1];
        acc[0] = hi ? b : a;
        acc[1] = hi ? a : b;
        acc[0] += __shfl_xor(acc[1], 4, 64);
    }
    acc[0] += __shfl_xor(acc[0], 8, 64);
    acc[0] += __shfl_xor(acc[0], 16, 64);
    acc[0] += __shfl_xor(acc[0], 32, 64);
}

// ---------------- Kernel 1: x_down = quick_gelu(x @ Wd + bd) ----------------
// v12 (best measured): wave per row-pair, 4 contiguous pairs per wave.
// 6 unique lane-contiguous NT float4 loads per pair (1 KB/instr); weights
// from LDS at use. Natural VGPR (no min-waves bound — R4/R10 showed bounds
// trigger occupancy-step spills), 24 KB LDS -> 6 blocks/CU = 24 waves/CU.
// Runs at ~2.9 TB/s read = the chip's practical streaming-read ceiling
// (verified across 7 structurally distinct variants, R1-R12).
__global__ __launch_bounds__(256) void k_down(
    const float* __restrict__ x, const float* __restrict__ Wd,
    const float* __restrict__ bd, float* __restrict__ t1)
{
    __shared__ float sW[D_ * C_];   // transposed: sW[d*C_ + c] = Wd[c*D_ + d]
    for (int i = threadIdx.x; i < D_ * C_; i += 256) {
        const int c = i >> 3, d = i & 7;
        sW[d * C_ + c] = Wd[i];     // Wd is [C][D] row-major
    }
    __syncthreads();

    const int wid  = threadIdx.x >> 6;
    const int lane = threadIdx.x & 63;
    const int dl   = 4 * (lane & 1) + 2 * ((lane >> 1) & 1) + ((lane >> 2) & 1);
    const float bias = bd[dl];

    const int gw = blockIdx.x * 4 + wid;   // 8192 waves x 4 pairs = 32768 pairs

#pragma unroll 1
    for (int i = 0; i < 4; ++i) {
        const int p = gw * 4 + i;          // contiguous 8 rows per wave
        const float4* x0 = (const float4*)(x + (size_t)(2 * p) * C_);
        const float4* x1 = x0 + (C_ / 4);

        float4 va[3], vb[3];
#pragma unroll
        for (int k = 0; k < 3; ++k) {
            va[k] = ntload4(&x0[k * 64 + lane]);
            vb[k] = ntload4(&x1[k * 64 + lane]);
        }

        float a0[D_], a1[D_];
#pragma unroll
        for (int d = 0; d < D_; ++d) { a0[d] = 0.0f; a1[d] = 0.0f; }

#pragma unroll
        for (int k = 0; k < 3; ++k) {
#pragma unroll
            for (int d = 0; d < D_; ++d) {
                const float4 wv = *(const float4*)&sW[d * C_ + (k * 64 + lane) * 4];
                a0[d] += va[k].x * wv.x + va[k].y * wv.y
                       + va[k].z * wv.z + va[k].w * wv.w;
                a1[d] += vb[k].x * wv.x + vb[k].y * wv.y
                       + vb[k].z * wv.z + vb[k].w * wv.w;
            }
        }

        reduce8(a0, lane);
        reduce8(a1, lane);

        if (lane < 16) {
            const float s = (lane & 8) ? a1[0] : a0[0];
            t1[(size_t)(2 * p + ((lane >> 3) & 1)) * D_ + dl] = qgelu(s + bias);
        }
    }
}

// ------------- Kernel 2: t2 = quick_gelu(conv3x3(t1) + bc) ------------------
__global__ __launch_bounds__(256, 4) void k_conv(
    const float* __restrict__ t1, const float* __restrict__ Wc,
    const float* __restrict__ bc, float* __restrict__ t2)
{
    __shared__ float sIn[10 * H_ * D_];     // 10 rows x 32 cols x 8 ch = 10 KB
    __shared__ float sWc[9 * D_ * D_];
    __shared__ float sbc[D_];

    const int img   = blockIdx.x >> 2;
    const int strip = blockIdx.x & 3;
    const int h0    = strip * 8;
    const float* in = t1 + (size_t)img * N_ * D_;

#pragma unroll
    for (int j = 0; j < 10; ++j) {
        const int i  = threadIdx.x + j * 256;
        const int lr = i >> 8;
        const int rem = i & 255;
        const int g  = h0 - 1 + lr;
        sIn[i] = (g >= 0 && g < H_) ? in[(size_t)g * H_ * D_ + rem] : 0.0f;
    }
    for (int i = threadIdx.x; i < 9 * D_ * D_; i += 256) sWc[i] = Wc[i];
    if (threadIdx.x < D_) sbc[threadIdx.x] = bc[threadIdx.x];
    __syncthreads();

    const int lh = threadIdx.x >> 5;
    const int w  = threadIdx.x & 31;
    float acc[D_];
#pragma unroll
    for (int co = 0; co < D_; ++co) acc[co] = sbc[co];

#pragma unroll
    for (int kh = 0; kh < 3; ++kh) {
        const int lrow = lh + kh;
#pragma unroll
        for (int kw = 0; kw < 3; ++kw) {
            const int ww = w + kw - 1;
            if (ww < 0 || ww >= H_) continue;
            const float* ip = &sIn[(lrow * H_ + ww) * D_];
            const float* wp = &sWc[(kh * 3 + kw) * D_ * D_];
#pragma unroll
            for (int ci = 0; ci < D_; ++ci) {
                const float iv = ip[ci];
#pragma unroll
                for (int co = 0; co < D_; ++co)
                    acc[co] += iv * wp[ci * D_ + co];
            }
        }
    }
    float4 o0, o1;
    o0.x = qgelu(acc[0]); o0.y = qgelu(acc[1]);
    o0.z = qgelu(acc[2]); o0.w = qgelu(acc[3]);
    o1.x = qgelu(acc[4]); o1.y = qgelu(acc[5]);
    o1.z = qgelu(acc[6]); o1.w = qgelu(acc[7]);
    float* tp = t2 + ((size_t)img * N_ + (size_t)(h0 + lh) * H_ + w) * D_;
    *(float4*)tp       = o0;
    *(float4*)(tp + 4) = o1;
}

// ---------------- Kernel 3: out = t2 @ Wu + bu ------------------------------
// Register-weight, LDS-free, nt out stores (~7 TB/s write wall).
__global__ __launch_bounds__(256, 3) void k_up(
    const float* __restrict__ t2, const float* __restrict__ Wu,
    const float* __restrict__ bu, float* __restrict__ out, int nrows)
{
    const int wid  = threadIdx.x >> 6;
    const int lane = threadIdx.x & 63;

    float4 w[3][D_];
    float4 bias[3];
#pragma unroll
    for (int j = 0; j < 3; ++j) {
        bias[j] = *(const float4*)&bu[(lane + j * 64) * 4];
#pragma unroll
        for (int d = 0; d < D_; ++d)
            w[j][d] = *(const float4*)&Wu[d * C_ + (lane + j * 64) * 4];
    }

    const int stride = gridDim.x * 4;
    for (int row = blockIdx.x * 4 + wid; row < nrows; row += stride) {
        const float4* rp = (const float4*)(t2 + (size_t)row * D_);
        const float4 ra = rp[0];
        const float4 rb = rp[1];
        const float rv[D_] = { ra.x, ra.y, ra.z, ra.w, rb.x, rb.y, rb.z, rb.w };

#pragma unroll
        for (int j = 0; j < 3; ++j) {
            float4 o = bias[j];
#pragma unroll
            for (int d = 0; d < D_; ++d) {
                o.x += rv[d] * w[j][d].x;
                o.y += rv[d] * w[j][d].y;
                o.z += rv[d] * w[j][d].z;
                o.w += rv[d] * w[j][d].w;
            }
            ntstore4(o, (float4*)&out[(size_t)row * C_ + (size_t)(lane + j * 64) * 4]);
        }
    }
}

extern "C" void kernel_launch(void* const* d_in, const int* in_sizes, int n_in,
                              void* d_out, int out_size, void* d_ws, size_t ws_size,
                              hipStream_t stream) {
    const float* x  = (const float*)d_in[0];
    const float* Wd = (const float*)d_in[1];
    const float* bd = (const float*)d_in[2];
    const float* Wc = (const float*)d_in[3];
    const float* bc = (const float*)d_in[4];
    const float* Wu = (const float*)d_in[5];
    const float* bu = (const float*)d_in[6];
    float* out = (float*)d_out;

    const int nrows = B_ * N_;                  // 65536
    float* t1 = (float*)d_ws;                   // [nrows][D_]  (2 MB)
    float* t2 = t1 + (size_t)nrows * D_;        // [nrows][D_]  (2 MB)

    // K1 v12: 2048 blocks x 4 waves x 4 pairs = 32768 pairs exactly; nt loads.
    k_down<<<2048, 256, 0, stream>>>(x, Wd, bd, t1);
    // K2: 4 blocks per image
    k_conv<<<B_ * 4, 256, 0, stream>>>(t1, Wc, bc, t2);
    // K3: register-weight, LDS-free, nt out stores.
    k_up<<<768, 256, 0, stream>>>(t2, Wu, bu, out, nrows);
}